// Round 1
// 142.215 us; speedup vs baseline: 1.0192x; 1.0192x over previous
//
#include <hip/hip_runtime.h>
#include <hip/hip_bf16.h>

#define NSP 4096      // D*H*W
#define CH 256
#define NB 2
#define NG 8
#define CPG 32        // channels per group
#define NHD 4         // heads
#define HDIM 64       // head dim

typedef unsigned short u16;
typedef unsigned int u32;
typedef __attribute__((ext_vector_type(8))) short bf16x8;
typedef __attribute__((ext_vector_type(4))) float f32x4;

#define MFMA __builtin_amdgcn_mfma_f32_16x16x32_bf16
#define QSCALE 0.18033688f   // 0.125 * log2(e): folds attn scale + exp2 domain

__device__ __forceinline__ u16 f2bf(float f) {
    u32 i = __float_as_uint(f);
    u32 r = (i + 0x7FFFu + ((i >> 16) & 1u)) >> 16;   // round-nearest-even
    return (u16)r;
}

// async global->LDS DMA: wave loads 1 KB (16 B/lane); lds dst = uniform base + lane*16
__device__ __forceinline__ void dma16(const u16* g, u16* l) {
    __builtin_amdgcn_global_load_lds(
        (const __attribute__((address_space(1))) void*)g,
        (__attribute__((address_space(3))) void*)l, 16, 0, 0);
}

// ------- fused prep: weight fp32->bf16 (XOR-chunk-swizzled rows) + GN partials -------
// Weight rows [m][256] stored with 16B chunk c at position c^(m&7) -- makes the
// gemm kernels' DMA-staged LDS image conflict-minimal (same idiom as qT/kT).
__global__ __launch_bounds__(256) void prep(const float* __restrict__ qw,
                                            const float* __restrict__ pw,
                                            u16* __restrict__ wqb,
                                            u16* __restrict__ wpb,
                                            const float* __restrict__ x,
                                            float* __restrict__ partial) {
    if (blockIdx.x < 256) {
        int i = (blockIdx.x * 256 + threadIdx.x) * 4;
        const float* src; u16* dstbase; int j;
        if (i < 3 * CH * CH) { src = qw + i; dstbase = wqb; j = i; }
        else { j = i - 3 * CH * CH; src = pw + j; dstbase = wpb; }
        int m = j >> 8, c = j & 255;
        int dc = ((((c >> 3) ^ (m & 7)) << 3)) | (c & 7);
        float4 v = *(const float4*)src;
        ushort4 o;
        o.x = f2bf(v.x); o.y = f2bf(v.y); o.z = f2bf(v.z); o.w = f2bf(v.w);
        *(ushort4*)(dstbase + (m << 8) + dc) = o;
        return;
    }
    const int id = blockIdx.x - 256;
    const int bg = id >> 4, chunk = id & 15;
    const float* p = x + (size_t)bg * (CPG * NSP) + chunk * 8192;
    float s = 0.f, ss = 0.f;
    for (int i = threadIdx.x; i < 2048; i += 256) {   // 8192 floats
        float4 u = ((const float4*)p)[i];
        s += u.x + u.y + u.z + u.w;
        ss += u.x * u.x + u.y * u.y + u.z * u.z + u.w * u.w;
    }
    for (int off = 32; off > 0; off >>= 1) {
        s += __shfl_down(s, off);
        ss += __shfl_down(ss, off);
    }
    __shared__ float red[4][2];
    const int wv = threadIdx.x >> 6;
    if ((threadIdx.x & 63) == 0) { red[wv][0] = s; red[wv][1] = ss; }
    __syncthreads();
    if (threadIdx.x == 0) {
        float ts = red[0][0] + red[1][0] + red[2][0] + red[3][0];
        float tq = red[0][1] + red[1][1] + red[2][1] + red[3][1];
        partial[(bg * 16 + chunk) * 2]     = ts;
        partial[(bg * 16 + chunk) * 2 + 1] = tq;
    }
}

// ------- GroupNorm apply + transpose: x[b][c][n] fp32 -> xnT[b][n][c] bf16 -------
// xnT rows XOR-chunk-swizzled (chunk c at c^(n&7)) for gemm_qkv's DMA staging.
__global__ __launch_bounds__(256) void gn_apply_t(const float* __restrict__ x,
                                                  const float* __restrict__ partial,
                                                  const float* __restrict__ w,
                                                  const float* __restrict__ b,
                                                  u16* __restrict__ xnT) {
    __shared__ u16 T[64][72];   // [n][c], pitch 144 B
    const int n0 = blockIdx.x * 64, c0 = blockIdx.y * 64, bb = blockIdx.z;
    const int t = threadIdx.x;
    const int rc = t & 63;          // channel within tile
    const int g  = t >> 6;          // n-chunk group of 16
    const int c  = c0 + rc;
    const int bg = bb * NG + c / CPG;
    float s = 0.f, q = 0.f;
#pragma unroll
    for (int j = 0; j < 16; ++j) {
        s += partial[(bg * 16 + j) * 2];
        q += partial[(bg * 16 + j) * 2 + 1];
    }
    const float cnt = (float)(CPG * NSP);
    float mean = s / cnt;
    float var  = q / cnt - mean * mean;
    float rstd = rsqrtf(var + 1e-5f);
    float wf = w[c] * rstd, bv = b[c] - mean * wf;
    const float* px = x + ((size_t)bb * CH + c) * NSP + n0 + g * 16;
#pragma unroll
    for (int i = 0; i < 4; ++i) {
        float4 v = *(const float4*)(px + i * 4);
        T[g * 16 + i * 4 + 0][rc] = f2bf(v.x * wf + bv);
        T[g * 16 + i * 4 + 1][rc] = f2bf(v.y * wf + bv);
        T[g * 16 + i * 4 + 2][rc] = f2bf(v.z * wf + bv);
        T[g * 16 + i * 4 + 3][rc] = f2bf(v.w * wf + bv);
    }
    __syncthreads();
    int n = t >> 2, ch = (t & 3) * 16;
    uint4 o0 = *(const uint4*)&T[n][ch];
    uint4 o1 = *(const uint4*)&T[n][ch + 8];
    const int sw = n & 7;
    const int chunk0 = (c0 + ch) >> 3;
    u16* rowp = xnT + ((size_t)bb * NSP + n0 + n) * CH;
    *(uint4*)(rowp + ((chunk0 ^ sw) << 3))       = o0;
    *(uint4*)(rowp + (((chunk0 + 1) ^ sw) << 3)) = o1;
}

// ------- LDS-staged MFMA GEMM QKV: Y[m][n] = sum_c Aw[m][c]*xnT[n][c] + bias -------
// K=256 staged entirely: A-panel 64x256 + B-panel 64x256 = 64 KB via DMA, one
// barrier, pure LDS-fed MFMA. 2 blocks/CU. Inputs pre-swizzled by producers.
__global__ __launch_bounds__(256, 2) void gemm_qkv(const u16* __restrict__ Aw,
                                                   const float* __restrict__ bias,
                                                   const u16* __restrict__ xnT,
                                                   u16* __restrict__ qT,
                                                   u16* __restrict__ kT,
                                                   u16* __restrict__ v) {
    __shared__ u16 As[64][256];
    __shared__ u16 Bs[64][256];
    const int n0 = blockIdx.x * 64, m0 = blockIdx.y * 64, bb = blockIdx.z;
    const int wave = threadIdx.x >> 6, lane = threadIdx.x & 63;
    const int lq = lane & 15, quad = lane >> 4;
#pragma unroll
    for (int j = 0; j < 8; ++j) {       // 32 row-pairs (1 KB each) per array
        int r2 = (wave * 8 + j) * 2;
        dma16(Aw + (size_t)(m0 + r2) * CH + lane * 8, &As[r2][0]);
        dma16(xnT + ((size_t)bb * NSP + n0 + r2) * CH + lane * 8, &Bs[r2][0]);
    }
    __syncthreads();
    const int wm = (wave >> 1) * 32, wn = (wave & 1) * 32;
    const int sw = lq & 7;
    f32x4 acc[2][2] = {};
#pragma unroll
    for (int kk = 0; kk < 8; ++kk) {
        bf16x8 a[2], b[2];
#pragma unroll
        for (int mt = 0; mt < 2; ++mt)
            a[mt] = *(const bf16x8*)&As[wm + mt * 16 + lq][(((kk * 4 + quad) ^ sw)) << 3];
#pragma unroll
        for (int nt = 0; nt < 2; ++nt)
            b[nt] = *(const bf16x8*)&Bs[wn + nt * 16 + lq][(((kk * 4 + quad) ^ sw)) << 3];
#pragma unroll
        for (int mt = 0; mt < 2; ++mt)
#pragma unroll
            for (int nt = 0; nt < 2; ++nt)
                acc[mt][nt] = MFMA(a[mt], b[nt], acc[mt][nt], 0, 0, 0);
    }
    const int sect = m0 >> 8;              // 0=Q, 1=K, 2=V
    const int h = (m0 & 255) >> 6;         // head for Q/K sections
    const float osc = (sect == 0) ? QSCALE : 1.f;
#pragma unroll
    for (int im = 0; im < 2; ++im) {
        int ml = wm + im * 16 + quad * 4;  // +r, local m in [0,64)
        float4 bs = *(const float4*)(bias + m0 + ml);
#pragma unroll
        for (int in = 0; in < 2; ++in) {
            int n = n0 + wn + in * 16 + lq;
            f32x4 a = acc[im][in];
            float v0 = (a[0] + bs.x) * osc, v1 = (a[1] + bs.y) * osc;
            float v2 = (a[2] + bs.z) * osc, v3 = (a[3] + bs.w) * osc;
            if (sect < 2) {
                int lc = ml >> 3, sub = ml & 7;
                int colp = ((lc ^ (n & 7)) << 3) | sub;   // XOR chunk swizzle
                u16* base = (sect ? kT : qT) +
                            (((size_t)bb * NHD + h) * NSP + n) * HDIM + colp;
                ushort4 o;
                o.x = f2bf(v0); o.y = f2bf(v1); o.z = f2bf(v2); o.w = f2bf(v3);
                *(ushort4*)base = o;
            } else {
                float vv[4] = {v0, v1, v2, v3};
#pragma unroll
                for (int r = 0; r < 4; ++r) {
                    int ch = (m0 - 512) + ml + r;
                    // swizzle within the aligned 64-key block, keyed by ch&7
                    int pos = (n & ~63) + ((((n >> 3) & 7) ^ (ch & 7)) << 3) + (n & 7);
                    v[((size_t)bb * CH + ch) * NSP + pos] = f2bf(vv[r]);
                }
            }
        }
    }
}

// ---------------- attn11: 64-q blocks, 2 blocks/CU co-residency ----------------
// Restructured from attn10: qt dimension removed (16 q-rows/wave), grid doubled
// to 512 blocks. LDS carved to EXACTLY 81920 B = 160KiB/2 so two blocks
// co-reside per CU (4 waves/SIMD), hiding the per-iteration barrier + LDS
// latency that left 40% of cycles idle at 2 waves/SIMD.
//   Ks 32KB + Vs 32KB + Ps 16KB (8B-chunk XOR swizzle, conflict-optimal)
//   Ml aliases Ks[0][0] (buf0 unread in last iter); Obuf aliases Ps.
__global__ __launch_bounds__(512, 4) void attn11(const u16* __restrict__ qT,
                                                 const u16* __restrict__ kT,
                                                 const u16* __restrict__ vN,
                                                 u16* __restrict__ aoT) {
    __shared__ __align__(16) char smem[81920];
    u16 (*Ks)[2][64][64] = reinterpret_cast<u16(*)[2][64][64]>(smem);          // [kh][buf][key][ch]
    u16 (*Vs)[2][64][64] = reinterpret_cast<u16(*)[2][64][64]>(smem + 32768);  // [kh][buf][ch][key]
    u16* Ps = (u16*)(smem + 65536);       // [wave][16][64] u16, 8B-chunk XOR swizzled
    float* MlA = (float*)smem;            // [8][16] f32, aliases Ks[0][0] rows 0-3 (post-loop safe)
    float* Obuf = (float*)(smem + 65536); // [qg][16][64] f32, 16B-chunk XOR, aliases Ps

    const int h = blockIdx.y, bb = blockIdx.z;
    const int t = threadIdx.x;
    const int wave = t >> 6, lane = t & 63;
    const int qg = wave & 3, kh = wave >> 2;
    const int lq = lane & 15, quad = lane >> 4;
    const int q_lo = blockIdx.x * 64 + qg * 16;

    // Q fragments (swizzled global layout, pre-scaled by QSCALE), one 16-row q-tile
    const int pr = quad ^ (lq & 7);
    const u16* qrow0 = qT + (((size_t)bb * NHD + h) * NSP + q_lo + lq) * HDIM;
    bf16x8 qf0 = *(const bf16x8*)(qrow0 + pr * 8);
    bf16x8 qf1 = *(const bf16x8*)(qrow0 + (pr ^ 4) * 8);

    const u16* khead = kT + ((size_t)bb * NHD + h) * NSP * (size_t)HDIM;
    const u16* vhead = vN + ((size_t)bb * CH + h * HDIM) * NSP;

    // per-wave staging role: waves 0-3 stage K (kh_s = (wave>>1)&1), 4-7 stage V
    const int sK   = (wave < 4);
    const int kh_s = (wave >> 1) & 1;
    const int rbase = (wave & 1) * 32;
    // prologue: DMA tile 0 into buf 0
    {
#pragma unroll
        for (int j = 0; j < 4; ++j) {
            int r8 = rbase + j * 8;
            if (sK) {
                dma16(khead + (size_t)(kh_s * 2048 + r8) * HDIM + lane * 8,
                      &Ks[kh_s][0][r8][0]);
            } else {
                dma16(vhead + (size_t)(r8 + (lane >> 3)) * NSP + kh_s * 2048 + (lane & 7) * 8,
                      &Vs[kh_s][0][r8][0]);
            }
        }
    }

    u16* psrow = Ps + (wave * 16 + lq) * 64;   // this lane's P row (q = lq)
    const int sw2 = (lq & 7) << 1;             // 8B-chunk XOR key (even -> b128-safe)

    float l = 0.f;
    f32x4 O[4] = {};
    for (int kt = 0; kt < 32; ++kt) {
        const int cur = kt & 1;
        __syncthreads();   // drains this wave's DMA (vmcnt 0) + syncs buffers
        if (kt < 31) {     // DMA tile kt+1 into buf cur^1, overlaps compute
            const int K1 = (kt + 1) * 64;
#pragma unroll
            for (int j = 0; j < 4; ++j) {
                int r8 = rbase + j * 8;
                if (sK) {
                    dma16(khead + (size_t)(kh_s * 2048 + K1 + r8) * HDIM + lane * 8,
                          &Ks[kh_s][cur ^ 1][r8][0]);
                } else {
                    dma16(vhead + (size_t)(r8 + (lane >> 3)) * NSP + kh_s * 2048 + K1 + (lane & 7) * 8,
                          &Vs[kh_s][cur ^ 1][r8][0]);
                }
            }
        }
        // S^T[key][q] (exp2-domain scores)
        f32x4 st[4];
#pragma unroll
        for (int mt = 0; mt < 4; ++mt) {
            bf16x8 a0 = *(const bf16x8*)&Ks[kh][cur][mt * 16 + lq][pr * 8];
            bf16x8 a1 = *(const bf16x8*)&Ks[kh][cur][mt * 16 + lq][(pr ^ 4) * 8];
            f32x4 acc = {0.f, 0.f, 0.f, 0.f};
            acc = MFMA(a0, qf0, acc, 0, 0, 0);
            acc = MFMA(a1, qf1, acc, 0, 0, 0);
            st[mt] = acc;
        }
        // max-free softmax numerator: p = exp2(s), accumulate l per lane
        float sum = 0.f;
#pragma unroll
        for (int mt = 0; mt < 4; ++mt) {
            float p0 = __builtin_amdgcn_exp2f(st[mt][0]);
            float p1 = __builtin_amdgcn_exp2f(st[mt][1]);
            float p2 = __builtin_amdgcn_exp2f(st[mt][2]);
            float p3 = __builtin_amdgcn_exp2f(st[mt][3]);
            sum += (p0 + p1) + (p2 + p3);
            // fast pack: round-half-up + v_perm pair-pack
            u32 r0 = __float_as_uint(p0) + 0x8000u;
            u32 r1 = __float_as_uint(p1) + 0x8000u;
            u32 r2 = __float_as_uint(p2) + 0x8000u;
            u32 r3 = __float_as_uint(p3) + 0x8000u;
            uint2 pkk;
            pkk.x = __builtin_amdgcn_perm(r1, r0, 0x07060302);
            pkk.y = __builtin_amdgcn_perm(r3, r2, 0x07060302);
            // chunk (mt*4+quad) XOR-swizzled within the row (chunks of 4 u16 = 8B)
            *(uint2*)(psrow + (((mt * 4 + quad) ^ sw2) << 2)) = pkk;
        }
        l += sum;
        // P fragments: keys quad*8..+7 (f=0) and 32+quad*8..+7 (f=1), q = lq
        bf16x8 pf0 = *(const bf16x8*)(psrow + ((((quad * 2)) ^ sw2) << 2));
        bf16x8 pf1 = *(const bf16x8*)(psrow + (((8 + quad * 2) ^ sw2) << 2));
        // PV: each Vs frag feeds 1 MFMA pair (no rescale -- fixed shift)
#pragma unroll
        for (int mtc = 0; mtc < 4; ++mtc) {
            bf16x8 v0 = *(const bf16x8*)&Vs[kh][cur][mtc * 16 + lq][pr * 8];
            bf16x8 v1 = *(const bf16x8*)&Vs[kh][cur][mtc * 16 + lq][(pr ^ 4) * 8];
            O[mtc] = MFMA(v0, pf0, O[mtc], 0, 0, 0);
            O[mtc] = MFMA(v1, pf1, O[mtc], 0, 0, 0);
        }
    }
    // ---- one-time l reduction (cross-quad) + 2-way key-half merge ----
    l += __shfl_xor(l, 16);
    l += __shfl_xor(l, 32);
    // Ml write aliases Ks[0][0] (buf 0): last iter (cur=1) only reads buf 1,
    // and all waves are past the kt=31 barrier -> no live reads of buf 0.
    if (lane < 16) MlA[wave * 16 + lane] = l;
    __syncthreads();   // Ml visible; all Ps reads done -> Obuf alias safe
    float gl = l + MlA[(wave ^ 4) * 16 + lq];
    if (kh == 1) {
#pragma unroll
        for (int mtc = 0; mtc < 4; ++mtc)
            *(f32x4*)&Obuf[((size_t)qg * 16 + lq) * 64 + (((mtc * 4 + quad) ^ lq) << 2)] = O[mtc];
    }
    __syncthreads();
    if (kh == 0) {
        const int sw = lq & 7;
        float linv = 1.f / gl;
        u16* rowp = aoT + ((size_t)bb * NSP + q_lo + lq) * CH;
#pragma unroll
        for (int mtc = 0; mtc < 4; ++mtc) {
            f32x4 sres = O[mtc] +
                         *(const f32x4*)&Obuf[((size_t)qg * 16 + lq) * 64 + (((mtc * 4 + quad) ^ lq) << 2)];
            ushort4 o;
            o.x = f2bf(sres[0] * linv);
            o.y = f2bf(sres[1] * linv);
            o.z = f2bf(sres[2] * linv);
            o.w = f2bf(sres[3] * linv);
            int chunk = (h << 3) | (mtc << 1) | (quad >> 1);
            int col = ((chunk ^ sw) << 3) | ((quad & 1) << 2);
            *(ushort4*)(rowp + col) = o;
        }
    }
}

// ------- LDS-staged MFMA GEMM proj: out = Pw.aoT + bias + x (fp32 epilogue) -------
__global__ __launch_bounds__(256, 2) void gemm_proj(const u16* __restrict__ Aw,
                                                    const float* __restrict__ bias,
                                                    const u16* __restrict__ aoT,
                                                    const float* __restrict__ xres,
                                                    float* __restrict__ out) {
    __shared__ u16 As[64][256];
    __shared__ u16 Bs[64][256];
    const int n0 = blockIdx.x * 64, m0 = blockIdx.y * 64, bb = blockIdx.z;
    const int wave = threadIdx.x >> 6, lane = threadIdx.x & 63;
    const int lq = lane & 15, quad = lane >> 4;
#pragma unroll
    for (int j = 0; j < 8; ++j) {
        int r2 = (wave * 8 + j) * 2;
        dma16(Aw + (size_t)(m0 + r2) * CH + lane * 8, &As[r2][0]);
        dma16(aoT + ((size_t)bb * NSP + n0 + r2) * CH + lane * 8, &Bs[r2][0]);
    }
    __syncthreads();
    const int wm = (wave >> 1) * 32, wn = (wave & 1) * 32;
    const int sw = lq & 7;
    f32x4 acc[2][2] = {};
#pragma unroll
    for (int kk = 0; kk < 8; ++kk) {
        bf16x8 a[2], b[2];
#pragma unroll
        for (int mt = 0; mt < 2; ++mt)
            a[mt] = *(const bf16x8*)&As[wm + mt * 16 + lq][(((kk * 4 + quad) ^ sw)) << 3];
#pragma unroll
        for (int nt = 0; nt < 2; ++nt)
            b[nt] = *(const bf16x8*)&Bs[wn + nt * 16 + lq][(((kk * 4 + quad) ^ sw)) << 3];
#pragma unroll
        for (int mt = 0; mt < 2; ++mt)
#pragma unroll
            for (int nt = 0; nt < 2; ++nt)
                acc[mt][nt] = MFMA(a[mt], b[nt], acc[mt][nt], 0, 0, 0);
    }
#pragma unroll
    for (int im = 0; im < 2; ++im) {
        int ml = wm + im * 16 + quad * 4;
        float4 bs = *(const float4*)(bias + m0 + ml);
        float bsv[4] = {bs.x, bs.y, bs.z, bs.w};
#pragma unroll
        for (int in = 0; in < 2; ++in) {
            int n = n0 + wn + in * 16 + lq;
            f32x4 a = acc[im][in];
#pragma unroll
            for (int r = 0; r < 4; ++r) {
                size_t idx = ((size_t)bb * CH + m0 + ml + r) * NSP + n;
                out[idx] = a[r] + bsv[r] + xres[idx];
            }
        }
    }
}

extern "C" void kernel_launch(void* const* d_in, const int* in_sizes, int n_in,
                              void* d_out, int out_size, void* d_ws, size_t ws_size,
                              hipStream_t stream) {
    const float* x      = (const float*)d_in[0];
    const float* norm_w = (const float*)d_in[1];
    const float* norm_b = (const float*)d_in[2];
    const float* qkv_w  = (const float*)d_in[3];
    const float* qkv_b  = (const float*)d_in[4];
    const float* proj_w = (const float*)d_in[5];
    const float* proj_b = (const float*)d_in[6];
    float* out = (float*)d_out;

    char* w = (char*)d_ws;
    float* partial = (float*)w;                       // 4 KB (16x16x2 fp32)
    u16* wqb = (u16*)(w + 4096);                      // 384 KB (768x256 bf16, swizzled)
    u16* wpb = (u16*)(w + 4096 + 393216);             // 128 KB (256x256 bf16, swizzled)
    u16* xnT = (u16*)(w + 528384);                    // 4 MB [b][n][c] swizzled (aliased by aoT)
    u16* qT  = (u16*)(w + 528384 + 4194304);          // 4 MB [b][h][n][64] swizzled, pre-scaled
    u16* kT  = (u16*)(w + 528384 + 2 * 4194304);      // 4 MB [b][h][n][64] swizzled
    u16* v   = (u16*)(w + 528384 + 3 * 4194304);      // 4 MB [b][c][n] swizzled blocks
    u16* aoT = xnT;                                   // xnT dead after gemm_qkv

    prep<<<dim3(512), 256, 0, stream>>>(qkv_w, proj_w, wqb, wpb, x, partial);
    gn_apply_t<<<dim3(NSP / 64, CH / 64, NB), 256, 0, stream>>>(
        x, partial, norm_w, norm_b, xnT);
    gemm_qkv<<<dim3(NSP / 64, (3 * CH) / 64, NB), 256, 0, stream>>>(
        wqb, qkv_b, xnT, qT, kT, v);
    attn11<<<dim3(NSP / 64, NHD, NB), 512, 0, stream>>>(qT, kT, v, aoT);
    gemm_proj<<<dim3(NSP / 64, CH / 64, NB), 256, 0, stream>>>(
        wpb, proj_b, aoT, x, out);
}

// Round 2
// 132.989 us; speedup vs baseline: 1.0899x; 1.0694x over previous
//
#include <hip/hip_runtime.h>
#include <hip/hip_bf16.h>

#define NSP 4096      // D*H*W
#define CH 256
#define NB 2
#define NG 8
#define CPG 32        // channels per group
#define NHD 4         // heads
#define HDIM 64       // head dim

typedef unsigned short u16;
typedef unsigned int u32;
typedef __attribute__((ext_vector_type(8))) short bf16x8;
typedef __attribute__((ext_vector_type(4))) float f32x4;
typedef __attribute__((ext_vector_type(16))) float f32x16;
typedef __attribute__((ext_vector_type(2))) unsigned int u32x2;
typedef __attribute__((ext_vector_type(4))) unsigned int u32x4;

#define MFMA __builtin_amdgcn_mfma_f32_16x16x32_bf16
#define MFMA32 __builtin_amdgcn_mfma_f32_32x32x16_bf16
#define QSCALE 0.18033688f   // 0.125 * log2(e): folds attn scale + exp2 domain

__device__ __forceinline__ u16 f2bf(float f) {
    u32 i = __float_as_uint(f);
    u32 r = (i + 0x7FFFu + ((i >> 16) & 1u)) >> 16;   // round-nearest-even
    return (u16)r;
}

// async global->LDS DMA: wave loads 1 KB (16 B/lane); lds dst = uniform base + lane*16
__device__ __forceinline__ void dma16(const u16* g, u16* l) {
    __builtin_amdgcn_global_load_lds(
        (const __attribute__((address_space(1))) void*)g,
        (__attribute__((address_space(3))) void*)l, 16, 0, 0);
}

// lane<32 keeps a, receives partner(lane+32)'s b; lane>=32 keeps b, receives
// partner(lane-32)'s a.  (V_PERMLANE32_SWAP_B32: vdst.hi <-> vsrc.lo)
__device__ __forceinline__ void plswap(u32& a, u32& b) {
#if __has_builtin(__builtin_amdgcn_permlane32_swap)
    u32x2 r = __builtin_amdgcn_permlane32_swap(a, b, false, false);
    a = r.x; b = r.y;
#else
    u32 sa = (u32)__shfl_xor((int)a, 32);
    u32 sb = (u32)__shfl_xor((int)b, 32);
    bool hi = (threadIdx.x & 32) != 0;
    u32 na = hi ? sb : a;
    u32 nb = hi ? b : sa;
    a = na; b = nb;
#endif
}

// ------- fused prep: weight fp32->bf16 (XOR-chunk-swizzled rows) + GN partials -------
__global__ __launch_bounds__(256) void prep(const float* __restrict__ qw,
                                            const float* __restrict__ pw,
                                            u16* __restrict__ wqb,
                                            u16* __restrict__ wpb,
                                            const float* __restrict__ x,
                                            float* __restrict__ partial) {
    if (blockIdx.x < 256) {
        int i = (blockIdx.x * 256 + threadIdx.x) * 4;
        const float* src; u16* dstbase; int j;
        if (i < 3 * CH * CH) { src = qw + i; dstbase = wqb; j = i; }
        else { j = i - 3 * CH * CH; src = pw + j; dstbase = wpb; }
        int m = j >> 8, c = j & 255;
        int dc = ((((c >> 3) ^ (m & 7)) << 3)) | (c & 7);
        float4 v = *(const float4*)src;
        ushort4 o;
        o.x = f2bf(v.x); o.y = f2bf(v.y); o.z = f2bf(v.z); o.w = f2bf(v.w);
        *(ushort4*)(dstbase + (m << 8) + dc) = o;
        return;
    }
    const int id = blockIdx.x - 256;
    const int bg = id >> 4, chunk = id & 15;
    const float* p = x + (size_t)bg * (CPG * NSP) + chunk * 8192;
    float s = 0.f, ss = 0.f;
    for (int i = threadIdx.x; i < 2048; i += 256) {   // 8192 floats
        float4 u = ((const float4*)p)[i];
        s += u.x + u.y + u.z + u.w;
        ss += u.x * u.x + u.y * u.y + u.z * u.z + u.w * u.w;
    }
    for (int off = 32; off > 0; off >>= 1) {
        s += __shfl_down(s, off);
        ss += __shfl_down(ss, off);
    }
    __shared__ float red[4][2];
    const int wv = threadIdx.x >> 6;
    if ((threadIdx.x & 63) == 0) { red[wv][0] = s; red[wv][1] = ss; }
    __syncthreads();
    if (threadIdx.x == 0) {
        float ts = red[0][0] + red[1][0] + red[2][0] + red[3][0];
        float tq = red[0][1] + red[1][1] + red[2][1] + red[3][1];
        partial[(bg * 16 + chunk) * 2]     = ts;
        partial[(bg * 16 + chunk) * 2 + 1] = tq;
    }
}

// ------- GroupNorm apply + transpose: x[b][c][n] fp32 -> xnT[b][n][c] bf16 -------
__global__ __launch_bounds__(256) void gn_apply_t(const float* __restrict__ x,
                                                  const float* __restrict__ partial,
                                                  const float* __restrict__ w,
                                                  const float* __restrict__ b,
                                                  u16* __restrict__ xnT) {
    __shared__ u16 T[64][72];   // [n][c], pitch 144 B
    const int n0 = blockIdx.x * 64, c0 = blockIdx.y * 64, bb = blockIdx.z;
    const int t = threadIdx.x;
    const int rc = t & 63;          // channel within tile
    const int g  = t >> 6;          // n-chunk group of 16
    const int c  = c0 + rc;
    const int bg = bb * NG + c / CPG;
    float s = 0.f, q = 0.f;
#pragma unroll
    for (int j = 0; j < 16; ++j) {
        s += partial[(bg * 16 + j) * 2];
        q += partial[(bg * 16 + j) * 2 + 1];
    }
    const float cnt = (float)(CPG * NSP);
    float mean = s / cnt;
    float var  = q / cnt - mean * mean;
    float rstd = rsqrtf(var + 1e-5f);
    float wf = w[c] * rstd, bv = b[c] - mean * wf;
    const float* px = x + ((size_t)bb * CH + c) * NSP + n0 + g * 16;
#pragma unroll
    for (int i = 0; i < 4; ++i) {
        float4 v = *(const float4*)(px + i * 4);
        T[g * 16 + i * 4 + 0][rc] = f2bf(v.x * wf + bv);
        T[g * 16 + i * 4 + 1][rc] = f2bf(v.y * wf + bv);
        T[g * 16 + i * 4 + 2][rc] = f2bf(v.z * wf + bv);
        T[g * 16 + i * 4 + 3][rc] = f2bf(v.w * wf + bv);
    }
    __syncthreads();
    int n = t >> 2, ch = (t & 3) * 16;
    uint4 o0 = *(const uint4*)&T[n][ch];
    uint4 o1 = *(const uint4*)&T[n][ch + 8];
    const int sw = n & 7;
    const int chunk0 = (c0 + ch) >> 3;
    u16* rowp = xnT + ((size_t)bb * NSP + n0 + n) * CH;
    *(uint4*)(rowp + ((chunk0 ^ sw) << 3))       = o0;
    *(uint4*)(rowp + (((chunk0 + 1) ^ sw) << 3)) = o1;
}

// ------- LDS-staged MFMA GEMM QKV -------
__global__ __launch_bounds__(256, 2) void gemm_qkv(const u16* __restrict__ Aw,
                                                   const float* __restrict__ bias,
                                                   const u16* __restrict__ xnT,
                                                   u16* __restrict__ qT,
                                                   u16* __restrict__ kT,
                                                   u16* __restrict__ v) {
    __shared__ u16 As[64][256];
    __shared__ u16 Bs[64][256];
    const int n0 = blockIdx.x * 64, m0 = blockIdx.y * 64, bb = blockIdx.z;
    const int wave = threadIdx.x >> 6, lane = threadIdx.x & 63;
    const int lq = lane & 15, quad = lane >> 4;
#pragma unroll
    for (int j = 0; j < 8; ++j) {       // 32 row-pairs (1 KB each) per array
        int r2 = (wave * 8 + j) * 2;
        dma16(Aw + (size_t)(m0 + r2) * CH + lane * 8, &As[r2][0]);
        dma16(xnT + ((size_t)bb * NSP + n0 + r2) * CH + lane * 8, &Bs[r2][0]);
    }
    __syncthreads();
    const int wm = (wave >> 1) * 32, wn = (wave & 1) * 32;
    const int sw = lq & 7;
    f32x4 acc[2][2] = {};
#pragma unroll
    for (int kk = 0; kk < 8; ++kk) {
        bf16x8 a[2], b[2];
#pragma unroll
        for (int mt = 0; mt < 2; ++mt)
            a[mt] = *(const bf16x8*)&As[wm + mt * 16 + lq][(((kk * 4 + quad) ^ sw)) << 3];
#pragma unroll
        for (int nt = 0; nt < 2; ++nt)
            b[nt] = *(const bf16x8*)&Bs[wn + nt * 16 + lq][(((kk * 4 + quad) ^ sw)) << 3];
#pragma unroll
        for (int mt = 0; mt < 2; ++mt)
#pragma unroll
            for (int nt = 0; nt < 2; ++nt)
                acc[mt][nt] = MFMA(a[mt], b[nt], acc[mt][nt], 0, 0, 0);
    }
    const int sect = m0 >> 8;              // 0=Q, 1=K, 2=V
    const int h = (m0 & 255) >> 6;         // head for Q/K sections
    const float osc = (sect == 0) ? QSCALE : 1.f;
#pragma unroll
    for (int im = 0; im < 2; ++im) {
        int ml = wm + im * 16 + quad * 4;  // +r, local m in [0,64)
        float4 bs = *(const float4*)(bias + m0 + ml);
#pragma unroll
        for (int in = 0; in < 2; ++in) {
            int n = n0 + wn + in * 16 + lq;
            f32x4 a = acc[im][in];
            float v0 = (a[0] + bs.x) * osc, v1 = (a[1] + bs.y) * osc;
            float v2 = (a[2] + bs.z) * osc, v3 = (a[3] + bs.w) * osc;
            if (sect < 2) {
                int lc = ml >> 3, sub = ml & 7;
                int colp = ((lc ^ (n & 7)) << 3) | sub;   // XOR chunk swizzle
                u16* base = (sect ? kT : qT) +
                            (((size_t)bb * NHD + h) * NSP + n) * HDIM + colp;
                ushort4 o;
                o.x = f2bf(v0); o.y = f2bf(v1); o.z = f2bf(v2); o.w = f2bf(v3);
                *(ushort4*)base = o;
            } else {
                float vv[4] = {v0, v1, v2, v3};
#pragma unroll
                for (int r = 0; r < 4; ++r) {
                    int ch = (m0 - 512) + ml + r;
                    // swizzle within the aligned 64-key block, keyed by ch&7
                    int pos = (n & ~63) + ((((n >> 3) & 7) ^ (ch & 7)) << 3) + (n & 7);
                    v[((size_t)bb * CH + ch) * NSP + pos] = f2bf(vv[r]);
                }
            }
        }
    }
}

// ---------------- attn12: 32x32 MFMA core, zero-LDS softmax redistribution ----------------
// Revised theory: attn10/11 were LDS-bandwidth-bound (224 KB LDS traffic per
// 128-key step).  This version cuts LDS bytes per unit work 2.3x:
//   * mfma_f32_32x32x16_bf16, 64 q-rows/wave (2 qtiles) -> K/V fragment reads
//     amortized 2x (64 KB vs 128 KB per 128-key-equivalent)
//   * P never touches LDS: S->P B-fragment redistribution is a pure
//     lane<->lane+32 exchange (pack + permlane32_swap, T12 idiom)
//   * keys split 4 ways across waves; 256 keys staged per step -> 16 barriers
// LDS = Ks[4][2][64][64] + Vs[4][2][64][64] = 128 KB (1 block/CU).
__global__ __launch_bounds__(512, 2) void attn12(const u16* __restrict__ qT,
                                                 const u16* __restrict__ kT,
                                                 const u16* __restrict__ vN,
                                                 u16* __restrict__ aoT) {
    __shared__ __align__(16) char smem[131072];
    u16 (*Ks)[2][64][64] = reinterpret_cast<u16(*)[2][64][64]>(smem);          // [slice][buf][key][ch]
    u16 (*Vs)[2][64][64] = reinterpret_cast<u16(*)[2][64][64]>(smem + 65536);  // [slice][buf][ch][key]

    const int h = blockIdx.y, bb = blockIdx.z;
    const int t = threadIdx.x;
    const int wave = t >> 6, lane = t & 63;
    const int l31 = lane & 31, hi = lane >> 5, ln7 = lane & 7;
    const int qg = wave >> 2;        // q-group: 64 rows
    const int csl = wave & 3;        // compute key-slice (keys csl*1024 ..)
    const int q_lo = blockIdx.x * 128 + qg * 64;

    // Q fragments: B-operand of 32x32x16 (n=q=lane&31, k=8*hi+j), chunk-swizzled global
    bf16x8 qf[2][4];
#pragma unroll
    for (int qt = 0; qt < 2; ++qt) {
        const u16* qrow = qT + (((size_t)bb * NHD + h) * NSP + q_lo + qt * 32 + l31) * HDIM;
#pragma unroll
        for (int d = 0; d < 4; ++d)
            qf[qt][d] = *(const bf16x8*)(qrow + (((d * 2 + hi) ^ ln7) << 3));
    }

    const u16* khead = kT + ((size_t)bb * NHD + h) * NSP * (size_t)HDIM;
    const u16* vhead = vN + ((size_t)bb * CH + h * HDIM) * NSP;

    // staging role: waves 0-3 stage K slice (wave), waves 4-7 stage V slice (wave-4)
    const int sV  = wave >> 2;
    const int ssl = wave & 3;
    int koff[4];
#pragma unroll
    for (int d = 0; d < 4; ++d) koff[d] = (((d * 2 + hi) ^ ln7) << 3);

    // prologue: DMA step 0 into buf 0 (8 KB per wave = 8 x 1 KB)
#pragma unroll
    for (int j = 0; j < 8; ++j) {
        if (sV == 0)
            dma16(khead + (size_t)(ssl * 1024 + j * 8) * HDIM + lane * 8,
                  &Ks[ssl][0][j * 8][0]);
        else
            dma16(vhead + (size_t)(j * 8 + (lane >> 3)) * NSP + ssl * 1024 + (lane & 7) * 8,
                  &Vs[ssl][0][j * 8][0]);
    }

    float l[2] = {0.f, 0.f};
    f32x16 O[2][2] = {};     // [qt][chtile]
    for (int kt = 0; kt < 16; ++kt) {
        const int cur = kt & 1;
        __syncthreads();     // drains DMA (vmcnt 0) + syncs buffers
        if (kt < 15) {       // DMA step kt+1 into buf cur^1, overlaps compute
            const int K1 = (kt + 1) * 64;
#pragma unroll
            for (int j = 0; j < 8; ++j) {
                if (sV == 0)
                    dma16(khead + (size_t)(ssl * 1024 + K1 + j * 8) * HDIM + lane * 8,
                          &Ks[ssl][cur ^ 1][j * 8][0]);
                else
                    dma16(vhead + (size_t)(j * 8 + (lane >> 3)) * NSP + ssl * 1024 + K1 + (lane & 7) * 8,
                          &Vs[ssl][cur ^ 1][j * 8][0]);
            }
        }
#pragma unroll
        for (int ktile = 0; ktile < 2; ++ktile) {
            u32x4 pf[2][2];      // [qt][kstep] B-fragments (8 bf16 each)
#pragma unroll
            for (int qt = 0; qt < 2; ++qt) {
                f32x16 acc = {};
#pragma unroll
                for (int d = 0; d < 4; ++d) {
                    bf16x8 kf = *(const bf16x8*)&Ks[csl][cur][ktile * 32 + l31][koff[d]];
                    acc = MFMA32(kf, qf[qt][d], acc, 0, 0, 0);
                }
                // p = exp2(s); C row = (reg&3) + 8*(reg>>2) + 4*hi
                float sum = 0.f;
                u32 pk_[8];
#pragma unroll
                for (int g = 0; g < 4; ++g) {
                    float p0 = __builtin_amdgcn_exp2f(acc[4 * g + 0]);
                    float p1 = __builtin_amdgcn_exp2f(acc[4 * g + 1]);
                    float p2 = __builtin_amdgcn_exp2f(acc[4 * g + 2]);
                    float p3 = __builtin_amdgcn_exp2f(acc[4 * g + 3]);
                    sum += (p0 + p1) + (p2 + p3);
                    u32 r0 = __float_as_uint(p0) + 0x8000u;
                    u32 r1 = __float_as_uint(p1) + 0x8000u;
                    u32 r2 = __float_as_uint(p2) + 0x8000u;
                    u32 r3 = __float_as_uint(p3) + 0x8000u;
                    pk_[2 * g]     = __builtin_amdgcn_perm(r1, r0, 0x07060302);
                    pk_[2 * g + 1] = __builtin_amdgcn_perm(r3, r2, 0x07060302);
                }
                l[qt] += sum;
                // redistribute to PV B-fragment (keys 16s+8hi+j): lane<->lane+32
                plswap(pk_[0], pk_[2]); plswap(pk_[1], pk_[3]);
                plswap(pk_[4], pk_[6]); plswap(pk_[5], pk_[7]);
                pf[qt][0][0] = pk_[0]; pf[qt][0][1] = pk_[1];
                pf[qt][0][2] = pk_[2]; pf[qt][0][3] = pk_[3];
                pf[qt][1][0] = pk_[4]; pf[qt][1][1] = pk_[5];
                pf[qt][1][2] = pk_[6]; pf[qt][1][3] = pk_[7];
            }
            // PV: each V fragment feeds both q-tiles
#pragma unroll
            for (int ct = 0; ct < 2; ++ct)
#pragma unroll
                for (int s = 0; s < 2; ++s) {
                    bf16x8 vf = *(const bf16x8*)
                        &Vs[csl][cur][ct * 32 + l31][(((ktile * 4 + s * 2 + hi) ^ ln7) << 3)];
                    bf16x8 pb0 = __builtin_bit_cast(bf16x8, pf[0][s]);
                    bf16x8 pb1 = __builtin_bit_cast(bf16x8, pf[1][s]);
                    O[0][ct] = MFMA32(vf, pb0, O[0][ct], 0, 0, 0);
                    O[1][ct] = MFMA32(vf, pb1, O[1][ct], 0, 0, 0);
                }
        }
    }
    // ---- l reduction across hi-halves, then 4-way slice merge through LDS ----
    l[0] += __shfl_xor(l[0], 32);
    l[1] += __shfl_xor(l[1], 32);
    __syncthreads();                         // B1: all Ks/Vs reads complete
    float* ob  = (float*)smem;               // 4 merge slots x 16 KB (Ks region)
    float* MlA = (float*)(smem + 65536);     // l table (Vs region)
    if (lane < 32) {
        MlA[(wave * 2 + 0) * 32 + l31] = l[0];
        MlA[(wave * 2 + 1) * 32 + l31] = l[1];
    }
    if (csl >= 2) {                          // Round A: slices 2,3 stage O
        int slot = qg * 2 + (csl - 2);
#pragma unroll
        for (int qt = 0; qt < 2; ++qt)
#pragma unroll
            for (int ct = 0; ct < 2; ++ct) {
                float* sp = ob + slot * 4096 + ((qt * 2 + ct) * 64 + lane) * 16;
#pragma unroll
                for (int cc = 0; cc < 4; ++cc) {
                    f32x4 tmp = {O[qt][ct][4 * cc + 0], O[qt][ct][4 * cc + 1],
                                 O[qt][ct][4 * cc + 2], O[qt][ct][4 * cc + 3]};
                    *(f32x4*)(sp + ((cc ^ (lane & 3)) << 2)) = tmp;
                }
            }
    }
    __syncthreads();                         // B2
    if (csl < 2) {                           // Round B: slices 0,1 absorb 2,3
        int slot = qg * 2 + csl;
#pragma unroll
        for (int qt = 0; qt < 2; ++qt)
#pragma unroll
            for (int ct = 0; ct < 2; ++ct) {
                float* sp = ob + slot * 4096 + ((qt * 2 + ct) * 64 + lane) * 16;
#pragma unroll
                for (int cc = 0; cc < 4; ++cc) {
                    f32x4 tmp = *(const f32x4*)(sp + ((cc ^ (lane & 3)) << 2));
                    O[qt][ct][4 * cc + 0] += tmp[0]; O[qt][ct][4 * cc + 1] += tmp[1];
                    O[qt][ct][4 * cc + 2] += tmp[2]; O[qt][ct][4 * cc + 3] += tmp[3];
                }
            }
    }
    __syncthreads();                         // B3
    if (csl == 1) {                          // Round C: slice 1 stages (1+3)
#pragma unroll
        for (int qt = 0; qt < 2; ++qt)
#pragma unroll
            for (int ct = 0; ct < 2; ++ct) {
                float* sp = ob + qg * 4096 + ((qt * 2 + ct) * 64 + lane) * 16;
#pragma unroll
                for (int cc = 0; cc < 4; ++cc) {
                    f32x4 tmp = {O[qt][ct][4 * cc + 0], O[qt][ct][4 * cc + 1],
                                 O[qt][ct][4 * cc + 2], O[qt][ct][4 * cc + 3]};
                    *(f32x4*)(sp + ((cc ^ (lane & 3)) << 2)) = tmp;
                }
            }
    }
    __syncthreads();                         // B4
    if (csl == 0) {                          // Round D: final sum, normalize, store
#pragma unroll
        for (int qt = 0; qt < 2; ++qt)
#pragma unroll
            for (int ct = 0; ct < 2; ++ct) {
                float* sp = ob + qg * 4096 + ((qt * 2 + ct) * 64 + lane) * 16;
#pragma unroll
                for (int cc = 0; cc < 4; ++cc) {
                    f32x4 tmp = *(const f32x4*)(sp + ((cc ^ (lane & 3)) << 2));
                    O[qt][ct][4 * cc + 0] += tmp[0]; O[qt][ct][4 * cc + 1] += tmp[1];
                    O[qt][ct][4 * cc + 2] += tmp[2]; O[qt][ct][4 * cc + 3] += tmp[3];
                }
            }
        float gl[2], linv[2];
#pragma unroll
        for (int qt = 0; qt < 2; ++qt) {
            gl[qt] = l[qt]
                   + MlA[((qg * 4 + 1) * 2 + qt) * 32 + l31]
                   + MlA[((qg * 4 + 2) * 2 + qt) * 32 + l31]
                   + MlA[((qg * 4 + 3) * 2 + qt) * 32 + l31];
            linv[qt] = 1.f / gl[qt];
        }
#pragma unroll
        for (int qt = 0; qt < 2; ++qt) {
            u16* rowp = aoT + ((size_t)bb * NSP + q_lo + qt * 32 + l31) * CH;
#pragma unroll
            for (int ct = 0; ct < 2; ++ct)
#pragma unroll
                for (int g = 0; g < 4; ++g) {
                    ushort4 o;
                    o.x = f2bf(O[qt][ct][4 * g + 0] * linv[qt]);
                    o.y = f2bf(O[qt][ct][4 * g + 1] * linv[qt]);
                    o.z = f2bf(O[qt][ct][4 * g + 2] * linv[qt]);
                    o.w = f2bf(O[qt][ct][4 * g + 3] * linv[qt]);
                    int chunk = h * 8 + ct * 4 + g;      // ch = ct*32 + 8g + 4hi
                    *(ushort4*)(rowp + ((chunk ^ ln7) << 3) + (hi << 2)) = o;
                }
        }
    }
}

// ------- LDS-staged MFMA GEMM proj: out = Pw.aoT + bias + x (fp32 epilogue) -------
__global__ __launch_bounds__(256, 2) void gemm_proj(const u16* __restrict__ Aw,
                                                    const float* __restrict__ bias,
                                                    const u16* __restrict__ aoT,
                                                    const float* __restrict__ xres,
                                                    float* __restrict__ out) {
    __shared__ u16 As[64][256];
    __shared__ u16 Bs[64][256];
    const int n0 = blockIdx.x * 64, m0 = blockIdx.y * 64, bb = blockIdx.z;
    const int wave = threadIdx.x >> 6, lane = threadIdx.x & 63;
    const int lq = lane & 15, quad = lane >> 4;
#pragma unroll
    for (int j = 0; j < 8; ++j) {
        int r2 = (wave * 8 + j) * 2;
        dma16(Aw + (size_t)(m0 + r2) * CH + lane * 8, &As[r2][0]);
        dma16(aoT + ((size_t)bb * NSP + n0 + r2) * CH + lane * 8, &Bs[r2][0]);
    }
    __syncthreads();
    const int wm = (wave >> 1) * 32, wn = (wave & 1) * 32;
    const int sw = lq & 7;
    f32x4 acc[2][2] = {};
#pragma unroll
    for (int kk = 0; kk < 8; ++kk) {
        bf16x8 a[2], b[2];
#pragma unroll
        for (int mt = 0; mt < 2; ++mt)
            a[mt] = *(const bf16x8*)&As[wm + mt * 16 + lq][(((kk * 4 + quad) ^ sw)) << 3];
#pragma unroll
        for (int nt = 0; nt < 2; ++nt)
            b[nt] = *(const bf16x8*)&Bs[wn + nt * 16 + lq][(((kk * 4 + quad) ^ sw)) << 3];
#pragma unroll
        for (int mt = 0; mt < 2; ++mt)
#pragma unroll
            for (int nt = 0; nt < 2; ++nt)
                acc[mt][nt] = MFMA(a[mt], b[nt], acc[mt][nt], 0, 0, 0);
    }
#pragma unroll
    for (int im = 0; im < 2; ++im) {
        int ml = wm + im * 16 + quad * 4;
        float4 bs = *(const float4*)(bias + m0 + ml);
        float bsv[4] = {bs.x, bs.y, bs.z, bs.w};
#pragma unroll
        for (int in = 0; in < 2; ++in) {
            int n = n0 + wn + in * 16 + lq;
            f32x4 a = acc[im][in];
#pragma unroll
            for (int r = 0; r < 4; ++r) {
                size_t idx = ((size_t)bb * CH + m0 + ml + r) * NSP + n;
                out[idx] = a[r] + bsv[r] + xres[idx];
            }
        }
    }
}

extern "C" void kernel_launch(void* const* d_in, const int* in_sizes, int n_in,
                              void* d_out, int out_size, void* d_ws, size_t ws_size,
                              hipStream_t stream) {
    const float* x      = (const float*)d_in[0];
    const float* norm_w = (const float*)d_in[1];
    const float* norm_b = (const float*)d_in[2];
    const float* qkv_w  = (const float*)d_in[3];
    const float* qkv_b  = (const float*)d_in[4];
    const float* proj_w = (const float*)d_in[5];
    const float* proj_b = (const float*)d_in[6];
    float* out = (float*)d_out;

    char* w = (char*)d_ws;
    float* partial = (float*)w;                       // 4 KB (16x16x2 fp32)
    u16* wqb = (u16*)(w + 4096);                      // 384 KB (768x256 bf16, swizzled)
    u16* wpb = (u16*)(w + 4096 + 393216);             // 128 KB (256x256 bf16, swizzled)
    u16* xnT = (u16*)(w + 528384);                    // 4 MB [b][n][c] swizzled (aliased by aoT)
    u16* qT  = (u16*)(w + 528384 + 4194304);          // 4 MB [b][h][n][64] swizzled, pre-scaled
    u16* kT  = (u16*)(w + 528384 + 2 * 4194304);      // 4 MB [b][h][n][64] swizzled
    u16* v   = (u16*)(w + 528384 + 3 * 4194304);      // 4 MB [b][c][n] swizzled blocks
    u16* aoT = xnT;                                   // xnT dead after gemm_qkv

    prep<<<dim3(512), 256, 0, stream>>>(qkv_w, proj_w, wqb, wpb, x, partial);
    gn_apply_t<<<dim3(NSP / 64, CH / 64, NB), 256, 0, stream>>>(
        x, partial, norm_w, norm_b, xnT);
    gemm_qkv<<<dim3(NSP / 64, (3 * CH) / 64, NB), 256, 0, stream>>>(
        wqb, qkv_b, xnT, qT, kT, v);
    attn12<<<dim3(NSP / 128, NHD, NB), 512, 0, stream>>>(qT, kT, v, aoT);
    gemm_proj<<<dim3(NSP / 64, CH / 64, NB), 256, 0, stream>>>(
        wpb, proj_b, aoT, x, out);
}